// Round 20
// baseline (546.950 us; speedup 1.0000x reference)
//
#include <hip/hip_runtime.h>
#include <hip/hip_fp16.h>
#include <math.h>

// Problem constants
#define NQ 40000

typedef short s16x8 __attribute__((ext_vector_type(8)));
typedef float f32x4 __attribute__((ext_vector_type(4)));

static constexpr int HLa[4] = {128, 64, 32, 16};
static constexpr int HWa[4] = {16384, 4096, 1024, 256};
// v bases (element units): level block is [HH][Hl][Wl][32]
static constexpr int VB[4] = {0, 4194304, 5242880, 5505024};
// total v elements = 5570560

__device__ __forceinline__ short bf16hi(float x) {
    union { float f; unsigned u; } v; v.f = x;
    unsigned r = v.u + 0x7FFFu + ((v.u >> 16) & 1u);
    return (short)(r >> 16);
}
__device__ __forceinline__ float bf16f(short s) {
    union { unsigned u; float f; } v; v.u = ((unsigned)(unsigned short)s) << 16;
    return v.f;
}
__device__ __forceinline__ float fast_tanh(float x) {
    float xc = fminf(fmaxf(x, -15.f), 15.f);
    float e = __expf(2.f * xc);
    return (e - 1.f) / (e + 1.f);
}
#define MFMA16(a, b, c) __builtin_amdgcn_mfma_f32_16x16x32_bf16(a, b, c, 0, 0, 0)

// ---------------------------------------------------------------------------
// Kernel 0: weight prep — transpose [C][N] -> [N][C], bf16 hi/lo split.
// rows: [0,512) = W_off cols, [512,768) = W_attn cols, [768,1024) = W_out cols
// ---------------------------------------------------------------------------
__global__ __launch_bounds__(256) void prep_w(
    const float* __restrict__ Woff, const float* __restrict__ Wattn,
    const float* __restrict__ Wout, short* __restrict__ WtH, short* __restrict__ WtL)
{
    int r = blockIdx.x, c = threadIdx.x;
    float x;
    if (r < 512)      x = Woff[c * 512 + r];
    else if (r < 768) x = Wattn[c * 256 + (r - 512)];
    else              x = Wout[c * 256 + (r - 768)];
    short hi = bf16hi(x);
    WtH[r * 256 + c] = hi;
    WtL[r * 256 + c] = bf16hi(x - bf16f(hi));
}

// ---------------------------------------------------------------------------
// Kernel 1: value projection -> fp16 table  v[l][hh][y][x][dd]
// ---------------------------------------------------------------------------
__global__ __launch_bounds__(256) void vproj_kernel(
    const float* __restrict__ f0, const float* __restrict__ f1,
    const float* __restrict__ f2, const float* __restrict__ f3,
    const float* __restrict__ Wv, const float* __restrict__ bv,
    __half* __restrict__ v)
{
    __shared__ float fT[256 * 16];  // [c][hw] 16KB

    int bid = blockIdx.x;
    const float* f;
    int base, HWl, hw0;
    if (bid < 1024)      { f = f0; base = VB[0]; HWl = 16384; hw0 = bid * 16; }
    else if (bid < 1280) { f = f1; base = VB[1]; HWl = 4096;  hw0 = (bid - 1024) * 16; }
    else if (bid < 1344) { f = f2; base = VB[2]; HWl = 1024;  hw0 = (bid - 1280) * 16; }
    else                 { f = f3; base = VB[3]; HWl = 256;   hw0 = (bid - 1344) * 16; }

    int t = threadIdx.x;
    for (int k = 0; k < 16; ++k) {
        int idx = k * 256 + t;
        int c = idx >> 4, j = idx & 15;
        fT[idx] = f[c * HWl + hw0 + j];
    }
    __syncthreads();

    int to4 = (t & 63) * 4;
    int hw4 = (t >> 6) * 4;

    float4 bv4 = *(const float4*)(bv + to4);
    float acc[4][4];
    #pragma unroll
    for (int i = 0; i < 4; ++i) {
        acc[i][0] = bv4.x; acc[i][1] = bv4.y; acc[i][2] = bv4.z; acc[i][3] = bv4.w;
    }

    #pragma unroll 4
    for (int c = 0; c < 256; ++c) {
        float4 w4 = *(const float4*)(Wv + c * 256 + to4);
        float4 fv = *(const float4*)(fT + c * 16 + hw4);
        float fa[4] = {fv.x, fv.y, fv.z, fv.w};
        float wa[4] = {w4.x, w4.y, w4.z, w4.w};
        #pragma unroll
        for (int i = 0; i < 4; ++i)
            #pragma unroll
            for (int j = 0; j < 4; ++j)
                acc[i][j] += fa[i] * wa[j];
    }

    int hh = to4 >> 5, dd4 = to4 & 31;
    #pragma unroll
    for (int i = 0; i < 4; ++i) {
        int hw = hw0 + hw4 + i;
        __half2 h0 = __floats2half2_rn(acc[i][0], acc[i][1]);
        __half2 h1 = __floats2half2_rn(acc[i][2], acc[i][3]);
        uint2 st = make_uint2(*(unsigned*)&h0, *(unsigned*)&h1);
        *(uint2*)(v + base + (hh * HWl + hw) * 32 + dd4) = st;
    }
}

// ---------------------------------------------------------------------------
// Kernel A: head-pair-specialized fused logits+pack+gather.
// SINGLE-WAVE BLOCKS: 64 threads, 10000 blocks. Each wave is fully
// autonomous (own 16 queries x 1 head-pair). LDS 7,680 B/block -> up to
// 20 blocks/CU (vs 3-4 for the 256-thread version) — attacks the gather's
// latency-bound plateau with raw wave supply (r14-r19 post-mortems: per-wave
// MLP is VGPR-capped; TLP is the remaining lever).
// hp = bid & 3; blocks round-robin XCDs (bid mod 8) so each XCD still serves
// one head-pair: 2.79MB v-slice fits 4MB L2 (r16-verified FETCH collapse).
// ---------------------------------------------------------------------------
__global__ __launch_bounds__(64, 8) void msda_hp_kernel(
    const float* __restrict__ query, const float* __restrict__ refp,
    const float* __restrict__ boff,  const float* __restrict__ battn,
    const short* __restrict__ WtH,   const short* __restrict__ WtL,
    const __half* __restrict__ v,    __half* __restrict__ preTg)
{
    __shared__ __align__(16) char lds[7680];
    // [0,4224):      offW [8][132] fp32 (superpass logits)
    // [4224,6400):   sWh [16][68] fp16 attn weights
    // [6400,6656):   sPIw [64] u32 records
    // [6656,7168):   sPWw [64] uint2 records
    // [7168,7680):   sR [128] fp32 ref points
    float*    offW = (float*)lds;
    __half*   sWh  = (__half*)(lds + 4224);
    unsigned* sPIw = (unsigned*)(lds + 6400);
    uint2*    sPWw = (uint2*)(lds + 6656);
    float*    sR   = (float*)(lds + 7168);

    const int lane = threadIdx.x;
    const int hp = blockIdx.x & 3;            // head-pair: heads {2hp, 2hp+1}
    const int n0 = (blockIdx.x >> 2) * 16;    // query base (16 queries/wave)
    const int mrow = lane & 15, kg = lane >> 4;

    // ---- Stage ref points for 16 queries (same-wave DS: no barrier) ----
    sR[lane]      = refp[n0 * 8 + lane];
    sR[lane + 64] = refp[n0 * 8 + 64 + lane];

    // ---- Logits via MFMA (hi/lo 3-pass), A inline from global fp32 ----
    f32x4 accO[8], accA[4];
    {
        f32x4 z = {0.f, 0.f, 0.f, 0.f};
        #pragma unroll
        for (int j = 0; j < 8; ++j) accO[j] = z;
        #pragma unroll
        for (int j = 0; j < 4; ++j) accA[j] = z;
    }
    {
        const float* qrow = query + (n0 + mrow) * 256 + kg * 8;
        const short* offH = WtH + (hp * 128 + mrow) * 256 + kg * 8;
        const short* offLo = WtL + (hp * 128 + mrow) * 256 + kg * 8;
        const short* attH = WtH + (512 + hp * 64 + mrow) * 256 + kg * 8;
        const short* attL = WtL + (512 + hp * 64 + mrow) * 256 + kg * 8;
        #pragma unroll
        for (int kk = 0; kk < 8; ++kk) {
            float4 qa = *(const float4*)(qrow + kk * 32);
            float4 qb = *(const float4*)(qrow + kk * 32 + 4);
            float qv[8] = {qa.x, qa.y, qa.z, qa.w, qb.x, qb.y, qb.z, qb.w};
            s16x8 ah, al;
            #pragma unroll
            for (int e = 0; e < 8; ++e) {
                short hi = bf16hi(qv[e]);
                ah[e] = hi;
                al[e] = bf16hi(qv[e] - bf16f(hi));
            }
            #pragma unroll
            for (int j = 0; j < 8; ++j) {
                s16x8 bh = *(const s16x8*)(offH + j * 4096 + kk * 32);
                s16x8 bl = *(const s16x8*)(offLo + j * 4096 + kk * 32);
                accO[j] = MFMA16(ah, bh, accO[j]);
                accO[j] = MFMA16(al, bh, accO[j]);
                accO[j] = MFMA16(ah, bl, accO[j]);
            }
            #pragma unroll
            for (int ja = 0; ja < 4; ++ja) {
                s16x8 bh = *(const s16x8*)(attH + ja * 4096 + kk * 32);
                s16x8 bl = *(const s16x8*)(attL + ja * 4096 + kk * 32);
                accA[ja] = MFMA16(ah, bh, accA[ja]);
                accA[ja] = MFMA16(al, bh, accA[ja]);
                accA[ja] = MFMA16(ah, bl, accA[ja]);
            }
        }
    }
    // biases (D layout: col = mrow, rows = kg*4 + r)
    #pragma unroll
    for (int j = 0; j < 8; ++j) {
        float bb = boff[hp * 128 + j * 16 + mrow];
        #pragma unroll
        for (int r = 0; r < 4; ++r) accO[j][r] += bb;
    }
    #pragma unroll
    for (int ja = 0; ja < 4; ++ja) {
        float bb = battn[hp * 64 + ja * 16 + mrow];
        #pragma unroll
        for (int r = 0; r < 4; ++r) accA[ja][r] += bb;
    }

    // ---- Softmax over P=8 (8-lane groups) -> sWh ----
    #pragma unroll
    for (int ja = 0; ja < 4; ++ja) {
        int hhL = ja >> 1;
        int l   = ((ja & 1) << 1) | (mrow >> 3);
        int p   = mrow & 7;
        #pragma unroll
        for (int r = 0; r < 4; ++r) {
            float x = accA[ja][r];
            float m = fmaxf(x, __shfl_xor(x, 1));
            m = fmaxf(m, __shfl_xor(m, 2));
            m = fmaxf(m, __shfl_xor(m, 4));
            float e = __expf(x - m);
            float s = e + __shfl_xor(e, 1);
            s += __shfl_xor(s, 2);
            s += __shfl_xor(s, 4);
            int ql = kg * 4 + r;
            sWh[ql * 68 + hhL * 32 + l * 8 + p] = __float2half_rn(e / s);
        }
    }

    // ---- Chunk-loop setup (all LDS wave-private; no barriers anywhere) ----
    const int l_p = (lane >> 3) & 3;
    const int Wl_p = 128 >> l_p;
    const float scl_p = 0.5f * (float)(Wl_p - 1);
    const int sg = kg, ch2 = mrow;
    const int Wl_s = 128 >> sg;
    const int HWs = Wl_s * Wl_s;
    const int dyoMul = Wl_s * 16;
    const int VBs = (sg == 0) ? VB[0] : (sg == 1) ? VB[1] : (sg == 2) ? VB[2] : VB[3];
    const __half2* vl0 = (const __half2*)(v + VBs + (2 * hp) * HWs * 32) + ch2;
    const __half2* vl1 = (const __half2*)(v + VBs + (2 * hp + 1) * HWs * 32) + ch2;

    for (int sp = 0; sp < 2; ++sp) {
        // dump: lanes holding q in [8sp, 8sp+8) write their accO rows
        if ((kg >> 1) == sp) {
            #pragma unroll
            for (int j = 0; j < 8; ++j)
                #pragma unroll
                for (int r = 0; r < 4; ++r)
                    offW[((kg & 1) * 4 + r) * 132 + j * 16 + mrow] = accO[j][r];
        }

        for (int c8 = 0; c8 < 8; ++c8) {
            const int ql = sp * 8 + c8;               // wave query 0..15
            // -- pack: each lane builds one record (lane = hhL*32 + l*8 + p) --
            {
                float2 ll = *(const float2*)(offW + c8 * 132 + 2 * lane);
                float lx = ll.x, ly = ll.y;
                float w  = __half2float(sWh[ql * 68 + lane]);
                float rx = sR[ql * 8 + l_p * 2], ry = sR[ql * 8 + l_p * 2 + 1];
                float cx = rx + fast_tanh(lx) * 0.25f;
                float cy = ry + fast_tanh(ly) * 0.25f;
                float xx = (cx + 1.f) * scl_p, yy = (cy + 1.f) * scl_p;
                float x0f = floorf(xx), y0f = floorf(yy);
                float fx = xx - x0f, fy = yy - y0f;
                int x0 = (int)x0f, y0 = (int)y0f;
                int xc0 = min(max(x0, 0), Wl_p - 1);
                int xc1 = min(max(x0 + 1, 0), Wl_p - 1);
                int yc0 = min(max(y0, 0), Wl_p - 1);
                int yc1 = min(max(y0 + 1, 0), Wl_p - 1);
                bool bx0 = (x0 >= 0) & (x0 < Wl_p);
                bool bx1 = (x0 + 1 >= 0) & (x0 + 1 < Wl_p);
                bool by0 = (y0 >= 0) & (y0 < Wl_p);
                bool by1 = (y0 + 1 >= 0) & (y0 + 1 < Wl_p);
                float w00 = (bx0 && by0) ? (1.f - fx) * (1.f - fy) * w : 0.f;
                float w01 = (bx1 && by0) ? fx * (1.f - fy) * w : 0.f;
                float w10 = (bx0 && by1) ? (1.f - fx) * fy * w : 0.f;
                float w11 = (bx1 && by1) ? fx * fy * w : 0.f;
                unsigned pw = (unsigned)(yc0 * Wl_p + xc0)
                            | ((unsigned)(xc1 - xc0) << 14)
                            | ((unsigned)(yc1 - yc0) << 15);
                sPIw[lane] = pw;
                __half2 hA = __floats2half2_rn(w00, w01);
                __half2 hB = __floats2half2_rn(w10, w11);
                sPWw[lane] = make_uint2(*(unsigned*)&hA, *(unsigned*)&hB);
            }

            // -- sample: per head, 32 gathers + blend --
            #pragma unroll
            for (int hhL = 0; hhL < 2; ++hhL) {
                const __half2* vl = hhL ? vl1 : vl0;
                float ax = 0.f, ay = 0.f;
                #pragma unroll
                for (int p = 0; p < 8; ++p) {
                    int rec = hhL * 32 + sg * 8 + p;
                    unsigned pw = sPIw[rec];
                    uint2 ww = sPWw[rec];
                    int idx = pw & 0x3FFF;
                    int dxo = ((pw >> 14) & 1) * 16;
                    int dyo = ((pw >> 15) & 1) * dyoMul;
                    const __half2* b00 = vl + idx * 16;
                    float2 fa = __half22float2(*(__half2*)&ww.x);   // (w00, w01)
                    float2 fb = __half22float2(*(__half2*)&ww.y);   // (w10, w11)
                    float2 f00 = __half22float2(b00[0]);
                    float2 f01 = __half22float2(b00[dxo]);
                    float2 f10 = __half22float2(b00[dyo]);
                    float2 f11 = __half22float2(b00[dxo + dyo]);
                    ax += fa.x * f00.x + fa.y * f01.x + fb.x * f10.x + fb.y * f11.x;
                    ay += fa.x * f00.y + fa.y * f01.y + fb.x * f10.y + fb.y * f11.y;
                }
                // reduce over levels (sg groups) and store this head
                float sxv = ax + __shfl_xor(ax, 16); sxv += __shfl_xor(sxv, 32);
                float syv = ay + __shfl_xor(ay, 16); syv += __shfl_xor(syv, 32);
                if (sg == 0)
                    *(__half2*)(preTg + (n0 + ql) * 256 + (2 * hp + hhL) * 32 + ch2 * 2) =
                        __floats2half2_rn(sxv, syv);
            }
        }
    }
}

// ---------------------------------------------------------------------------
// Kernel C: output projection  out = preT @ Wout + bout  (MFMA, hi/lo)
// block = 256 threads, 16 queries, 2500 blocks. LDS 16,896 B.
// ---------------------------------------------------------------------------
__global__ __launch_bounds__(256, 4) void outproj_kernel(
    const __half* __restrict__ preTg, const short* __restrict__ WtH,
    const short* __restrict__ WtL,    const float* __restrict__ bout,
    float* __restrict__ out)
{
    __shared__ __align__(16) char lds[16896];
    short* sQh = (short*)lds;
    short* sQl = (short*)(lds + 8448);

    const int t = threadIdx.x;
    const int n0 = blockIdx.x * 16;
    const int wv = t >> 6, lane = t & 63;
    const int mrow = lane & 15, kg = lane >> 4;

    {
        int q = t >> 4, seg = t & 15;       // coalesced: consecutive t -> +32B
        const uint2* src = (const uint2*)(preTg + (n0 + q) * 256 + seg * 16);
        short* dh = sQh + q * 264 + seg * 16;
        short* dl = sQl + q * 264 + seg * 16;
        #pragma unroll
        for (int jj = 0; jj < 4; ++jj) {
            uint2 u = src[jj];
            float2 fA = __half22float2(*(__half2*)&u.x);
            float2 fB = __half22float2(*(__half2*)&u.y);
            short h0 = bf16hi(fA.x), h1 = bf16hi(fA.y);
            short h2 = bf16hi(fB.x), h3 = bf16hi(fB.y);
            dh[4 * jj]     = h0;
            dh[4 * jj + 1] = h1;
            dh[4 * jj + 2] = h2;
            dh[4 * jj + 3] = h3;
            dl[4 * jj]     = bf16hi(fA.x - bf16f(h0));
            dl[4 * jj + 1] = bf16hi(fA.y - bf16f(h1));
            dl[4 * jj + 2] = bf16hi(fB.x - bf16f(h2));
            dl[4 * jj + 3] = bf16hi(fB.y - bf16f(h3));
        }
    }
    __syncthreads();

    f32x4 accE[4];
    f32x4 z = {0.f, 0.f, 0.f, 0.f};
    #pragma unroll
    for (int e = 0; e < 4; ++e) accE[e] = z;
    const short* outH = WtH + (768 + wv * 64 + mrow) * 256 + kg * 8;
    const short* outL = WtL + (768 + wv * 64 + mrow) * 256 + kg * 8;
    const int aoff = mrow * 264 + kg * 8;
    #pragma unroll
    for (int kk = 0; kk < 8; ++kk) {
        s16x8 ah = *(const s16x8*)(sQh + aoff + kk * 32);
        s16x8 al = *(const s16x8*)(sQl + aoff + kk * 32);
        #pragma unroll
        for (int e = 0; e < 4; ++e) {
            s16x8 bh = *(const s16x8*)(outH + e * 4096 + kk * 32);
            s16x8 bl = *(const s16x8*)(outL + e * 4096 + kk * 32);
            accE[e] = MFMA16(ah, bh, accE[e]);
            accE[e] = MFMA16(al, bh, accE[e]);
            accE[e] = MFMA16(ah, bl, accE[e]);
        }
    }
    #pragma unroll
    for (int e = 0; e < 4; ++e) {
        int col = wv * 64 + e * 16 + mrow;
        float bb = bout[col];
        #pragma unroll
        for (int r = 0; r < 4; ++r)
            out[(n0 + kg * 4 + r) * 256 + col] = accE[e][r] + bb;
    }
}

// ---------------------------------------------------------------------------
extern "C" void kernel_launch(void* const* d_in, const int* in_sizes, int n_in,
                              void* d_out, int out_size, void* d_ws, size_t ws_size,
                              hipStream_t stream) {
    const float* query = (const float*)d_in[0];
    const float* refp  = (const float*)d_in[1];
    const float* f0    = (const float*)d_in[2];
    const float* f1    = (const float*)d_in[3];
    const float* f2    = (const float*)d_in[4];
    const float* f3    = (const float*)d_in[5];
    const float* Woff  = (const float*)d_in[6];
    const float* boff  = (const float*)d_in[7];
    const float* Wattn = (const float*)d_in[8];
    const float* battn = (const float*)d_in[9];
    const float* Wval  = (const float*)d_in[10];
    const float* bval  = (const float*)d_in[11];
    const float* Wout  = (const float*)d_in[12];
    const float* bout  = (const float*)d_in[13];

    char* ws = (char*)d_ws;
    __half* v  = (__half*)ws;                          // 11,141,120 B
    short* WtH = (short*)(ws + 11141120);              //    524,288 B
    short* WtL = (short*)(ws + 11665408);              //    524,288 B
    __half* preTg = (__half*)(ws + 12189696);          // 20,480,000 B -> 32,669,696
    float* outp = (float*)d_out;

    prep_w<<<1024, 256, 0, stream>>>(Woff, Wattn, Wout, WtH, WtL);
    vproj_kernel<<<1360, 256, 0, stream>>>(f0, f1, f2, f3, Wval, bval, v);
    msda_hp_kernel<<<10000, 64, 0, stream>>>(query, refp, boff, battn,
                                             WtH, WtL, v, preTg);
    outproj_kernel<<<2500, 256, 0, stream>>>(preTg, WtH, WtL, bout, outp);
}

// Round 21
// 498.663 us; speedup vs baseline: 1.0968x; 1.0968x over previous
//
#include <hip/hip_runtime.h>
#include <hip/hip_fp16.h>
#include <math.h>

// Problem constants
#define NQ 40000

typedef short s16x8 __attribute__((ext_vector_type(8)));
typedef float f32x4 __attribute__((ext_vector_type(4)));

static constexpr int HLa[4] = {128, 64, 32, 16};
static constexpr int HWa[4] = {16384, 4096, 1024, 256};
// v bases (element units): level block is [HH][Hl][Wl][32]
static constexpr int VB[4] = {0, 4194304, 5242880, 5505024};
// total v elements = 5570560

__device__ __forceinline__ short bf16hi(float x) {
    union { float f; unsigned u; } v; v.f = x;
    unsigned r = v.u + 0x7FFFu + ((v.u >> 16) & 1u);
    return (short)(r >> 16);
}
__device__ __forceinline__ float bf16f(short s) {
    union { unsigned u; float f; } v; v.u = ((unsigned)(unsigned short)s) << 16;
    return v.f;
}
__device__ __forceinline__ float fast_tanh(float x) {
    float xc = fminf(fmaxf(x, -15.f), 15.f);
    float e = __expf(2.f * xc);
    return (e - 1.f) / (e + 1.f);
}
#define MFMA16(a, b, c) __builtin_amdgcn_mfma_f32_16x16x32_bf16(a, b, c, 0, 0, 0)

// ---------------------------------------------------------------------------
// Kernel 0: weight prep — transpose [C][N] -> [N][C], bf16 hi/lo split.
// rows: [0,512) = W_off cols, [512,768) = W_attn cols, [768,1024) = W_out cols
// ---------------------------------------------------------------------------
__global__ __launch_bounds__(256) void prep_w(
    const float* __restrict__ Woff, const float* __restrict__ Wattn,
    const float* __restrict__ Wout, short* __restrict__ WtH, short* __restrict__ WtL)
{
    int r = blockIdx.x, c = threadIdx.x;
    float x;
    if (r < 512)      x = Woff[c * 512 + r];
    else if (r < 768) x = Wattn[c * 256 + (r - 512)];
    else              x = Wout[c * 256 + (r - 768)];
    short hi = bf16hi(x);
    WtH[r * 256 + c] = hi;
    WtL[r * 256 + c] = bf16hi(x - bf16f(hi));
}

// ---------------------------------------------------------------------------
// Kernel 1: value projection -> fp16 table  v[l][hh][y][x][dd]
// ---------------------------------------------------------------------------
__global__ __launch_bounds__(256) void vproj_kernel(
    const float* __restrict__ f0, const float* __restrict__ f1,
    const float* __restrict__ f2, const float* __restrict__ f3,
    const float* __restrict__ Wv, const float* __restrict__ bv,
    __half* __restrict__ v)
{
    __shared__ float fT[256 * 16];  // [c][hw] 16KB

    int bid = blockIdx.x;
    const float* f;
    int base, HWl, hw0;
    if (bid < 1024)      { f = f0; base = VB[0]; HWl = 16384; hw0 = bid * 16; }
    else if (bid < 1280) { f = f1; base = VB[1]; HWl = 4096;  hw0 = (bid - 1024) * 16; }
    else if (bid < 1344) { f = f2; base = VB[2]; HWl = 1024;  hw0 = (bid - 1280) * 16; }
    else                 { f = f3; base = VB[3]; HWl = 256;   hw0 = (bid - 1344) * 16; }

    int t = threadIdx.x;
    for (int k = 0; k < 16; ++k) {
        int idx = k * 256 + t;
        int c = idx >> 4, j = idx & 15;
        fT[idx] = f[c * HWl + hw0 + j];
    }
    __syncthreads();

    int to4 = (t & 63) * 4;
    int hw4 = (t >> 6) * 4;

    float4 bv4 = *(const float4*)(bv + to4);
    float acc[4][4];
    #pragma unroll
    for (int i = 0; i < 4; ++i) {
        acc[i][0] = bv4.x; acc[i][1] = bv4.y; acc[i][2] = bv4.z; acc[i][3] = bv4.w;
    }

    #pragma unroll 4
    for (int c = 0; c < 256; ++c) {
        float4 w4 = *(const float4*)(Wv + c * 256 + to4);
        float4 fv = *(const float4*)(fT + c * 16 + hw4);
        float fa[4] = {fv.x, fv.y, fv.z, fv.w};
        float wa[4] = {w4.x, w4.y, w4.z, w4.w};
        #pragma unroll
        for (int i = 0; i < 4; ++i)
            #pragma unroll
            for (int j = 0; j < 4; ++j)
                acc[i][j] += fa[i] * wa[j];
    }

    int hh = to4 >> 5, dd4 = to4 & 31;
    #pragma unroll
    for (int i = 0; i < 4; ++i) {
        int hw = hw0 + hw4 + i;
        __half2 h0 = __floats2half2_rn(acc[i][0], acc[i][1]);
        __half2 h1 = __floats2half2_rn(acc[i][2], acc[i][3]);
        uint2 st = make_uint2(*(unsigned*)&h0, *(unsigned*)&h1);
        *(uint2*)(v + base + (hh * HWl + hw) * 32 + dd4) = st;
    }
}

// ---------------------------------------------------------------------------
// Kernel 2: MFMA logits -> 2 superpasses {per-wave 8-query logit dump ->
//           wave-autonomous per-query pack+gather} -> fp16 preT -> MFMA out.
// block = 256 threads (4 waves), 16 queries, 2500 blocks. LDS 28,928 B
// -> 5 blocks/CU.  preT ALIASES sWh: for chunk q each wave reads its own
// 64 attn-wt columns (pack) BEFORE writing the same 64 columns (preT) —
// same-wave DS ops are in-order; other waves' columns disjoint; E-stage
// reads after __syncthreads.
// ---------------------------------------------------------------------------
__global__ __launch_bounds__(256, 4) void msda_kernel(
    const float* __restrict__ query, const float* __restrict__ refp,
    const float* __restrict__ boff,  const float* __restrict__ battn,
    const float* __restrict__ bout,
    const short* __restrict__ WtH,   const short* __restrict__ WtL,
    const __half* __restrict__ v,    float* __restrict__ out)
{
    __shared__ __align__(16) char lds[28928];
    short*    sQh  = (short*)lds;                 // [16][264] bf16 hi (stage/E)
    short*    sQl  = (short*)(lds + 8448);        // [16][264] bf16 lo (stage/E)
    __half*   sWh  = (__half*)(lds + 16896);      // [16][264] attn wts -> preT (aliased)
    float*    sR   = (float*)(lds + 28416);       // [128] ref points

    const int t = threadIdx.x;
    const int n0 = blockIdx.x * 16;
    const int wv = t >> 6, lane = t & 63;
    const int mrow = lane & 15, kg = lane >> 4;
    float*    offW = (float*)lds + wv * 1056;     // per-wave [8][132] fp32 logits
    unsigned* sPIw = (unsigned*)(lds + 25344 + wv * 768);
    uint2*    sPWw = (uint2*)(lds + 25344 + wv * 768 + 256);
    __half*   preT = sWh;                          // alias (audited above)

    // ---- Stage: query -> bf16 hi/lo LDS, ref points ----
    for (int k2 = 0; k2 < 16; ++k2) {
        float x = query[(n0 + k2) * 256 + t];
        short hi = bf16hi(x);
        sQh[k2 * 264 + t] = hi;
        sQl[k2 * 264 + t] = bf16hi(x - bf16f(hi));
    }
    if (t < 128) sR[t] = refp[n0 * 8 + t];
    __syncthreads();

    // ---- Phase B: logits via MFMA (hi/lo 3-pass for off AND attn) ----
    f32x4 accO[8], accA[4];
    {
        f32x4 z = {0.f, 0.f, 0.f, 0.f};
        #pragma unroll
        for (int j = 0; j < 8; ++j) accO[j] = z;
        #pragma unroll
        for (int j = 0; j < 4; ++j) accA[j] = z;
    }
    {
        const short* offH = WtH + (wv * 128 + mrow) * 256 + kg * 8;
        const short* offLo = WtL + (wv * 128 + mrow) * 256 + kg * 8;
        const short* attH = WtH + (512 + wv * 64 + mrow) * 256 + kg * 8;
        const short* attL = WtL + (512 + wv * 64 + mrow) * 256 + kg * 8;
        const int aoff = mrow * 264 + kg * 8;
        #pragma unroll
        for (int kk = 0; kk < 8; ++kk) {
            s16x8 ah = *(const s16x8*)(sQh + aoff + kk * 32);
            s16x8 al = *(const s16x8*)(sQl + aoff + kk * 32);
            #pragma unroll
            for (int j = 0; j < 8; ++j) {
                s16x8 bh = *(const s16x8*)(offH + j * 4096 + kk * 32);
                s16x8 bl = *(const s16x8*)(offLo + j * 4096 + kk * 32);
                accO[j] = MFMA16(ah, bh, accO[j]);
                accO[j] = MFMA16(al, bh, accO[j]);
                accO[j] = MFMA16(ah, bl, accO[j]);
            }
            #pragma unroll
            for (int ja = 0; ja < 4; ++ja) {
                s16x8 bh = *(const s16x8*)(attH + ja * 4096 + kk * 32);
                s16x8 bl = *(const s16x8*)(attL + ja * 4096 + kk * 32);
                accA[ja] = MFMA16(ah, bh, accA[ja]);
                accA[ja] = MFMA16(al, bh, accA[ja]);
                accA[ja] = MFMA16(ah, bl, accA[ja]);
            }
        }
    }
    // biases (D layout: col = mrow, rows = kg*4 + r)
    #pragma unroll
    for (int j = 0; j < 8; ++j) {
        float bb = boff[wv * 128 + j * 16 + mrow];
        #pragma unroll
        for (int r = 0; r < 4; ++r) accO[j][r] += bb;
    }
    #pragma unroll
    for (int ja = 0; ja < 4; ++ja) {
        float bb = battn[wv * 64 + ja * 16 + mrow];
        #pragma unroll
        for (int r = 0; r < 4; ++r) accA[ja][r] += bb;
    }

    // ---- Softmax over P=8 (8-lane groups), fp16 weights to sWh (own heads) ----
    #pragma unroll
    for (int ja = 0; ja < 4; ++ja) {
        int hh = 2 * wv + (ja >> 1);
        int l  = ((ja & 1) << 1) | (mrow >> 3);
        int p  = mrow & 7;
        #pragma unroll
        for (int r = 0; r < 4; ++r) {
            float x = accA[ja][r];
            float m = fmaxf(x, __shfl_xor(x, 1));
            m = fmaxf(m, __shfl_xor(m, 2));
            m = fmaxf(m, __shfl_xor(m, 4));
            float e = __expf(x - m);
            float s = e + __shfl_xor(e, 1);
            s += __shfl_xor(s, 2);
            s += __shfl_xor(s, 4);
            int q = kg * 4 + r;
            sWh[q * 264 + hh * 32 + l * 8 + p] = __float2half_rn(e / s);
        }
    }
    __syncthreads();   // all waves done reading staged q; arena becomes offW

    // ---- Chunk-loop setup ----
    // pack mapping: lane = hhL*32 + l*8 + p  (one record per lane)
    const int l_p = (lane >> 3) & 3, p_p = lane & 7, hhL_p = lane >> 5;
    const int Wl_p = 128 >> l_p;
    const float scl_p = 0.5f * (float)(Wl_p - 1);
    const int whCol = (2 * wv + hhL_p) * 32 + l_p * 8 + p_p;
    // sample mapping: sg = lane>>4 owns level sg; ch2 = lane&15 channel pair
    const int sg = kg, ch2 = mrow;
    const int Wl_s = 128 >> sg;
    const int HWs = Wl_s * Wl_s;
    const int dyoMul = Wl_s * 16;
    const int VBs = (sg == 0) ? VB[0] : (sg == 1) ? VB[1] : (sg == 2) ? VB[2] : VB[3];
    const __half2* vl0 = (const __half2*)(v + VBs + (2 * wv) * HWs * 32) + ch2;
    const __half2* vl1 = (const __half2*)(v + VBs + (2 * wv + 1) * HWs * 32) + ch2;

    // ---- 2 superpasses x 8 queries, wave-autonomous ----
    for (int sp = 0; sp < 2; ++sp) {
        // dump: lanes holding q in [8sp, 8sp+8) write their accO rows
        if ((kg >> 1) == sp) {
            #pragma unroll
            for (int j = 0; j < 8; ++j)
                #pragma unroll
                for (int r = 0; r < 4; ++r)
                    offW[((kg & 1) * 4 + r) * 132 + j * 16 + mrow] = accO[j][r];
        }

        for (int c8 = 0; c8 < 8; ++c8) {
            const int chunk = sp * 8 + c8;
            // -- pack: each lane builds one record for (q=chunk, own head) --
            {
                float2 ll = *(const float2*)(offW + c8 * 132 + 2 * lane);
                float lx = ll.x, ly = ll.y;
                float w  = __half2float(sWh[chunk * 264 + whCol]);
                float rx = sR[chunk * 8 + l_p * 2], ry = sR[chunk * 8 + l_p * 2 + 1];
                float cx = rx + fast_tanh(lx) * 0.25f;
                float cy = ry + fast_tanh(ly) * 0.25f;
                float xx = (cx + 1.f) * scl_p, yy = (cy + 1.f) * scl_p;
                float x0f = floorf(xx), y0f = floorf(yy);
                float fx = xx - x0f, fy = yy - y0f;
                int x0 = (int)x0f, y0 = (int)y0f;
                int xc0 = min(max(x0, 0), Wl_p - 1);
                int xc1 = min(max(x0 + 1, 0), Wl_p - 1);
                int yc0 = min(max(y0, 0), Wl_p - 1);
                int yc1 = min(max(y0 + 1, 0), Wl_p - 1);
                bool bx0 = (x0 >= 0) & (x0 < Wl_p);
                bool bx1 = (x0 + 1 >= 0) & (x0 + 1 < Wl_p);
                bool by0 = (y0 >= 0) & (y0 < Wl_p);
                bool by1 = (y0 + 1 >= 0) & (y0 + 1 < Wl_p);
                float w00 = (bx0 && by0) ? (1.f - fx) * (1.f - fy) * w : 0.f;
                float w01 = (bx1 && by0) ? fx * (1.f - fy) * w : 0.f;
                float w10 = (bx0 && by1) ? (1.f - fx) * fy * w : 0.f;
                float w11 = (bx1 && by1) ? fx * fy * w : 0.f;
                unsigned pw = (unsigned)(yc0 * Wl_p + xc0)
                            | ((unsigned)(xc1 - xc0) << 14)
                            | ((unsigned)(yc1 - yc0) << 15);
                sPIw[lane] = pw;
                __half2 hA = __floats2half2_rn(w00, w01);
                __half2 hB = __floats2half2_rn(w10, w11);
                sPWw[lane] = make_uint2(*(unsigned*)&hA, *(unsigned*)&hB);
            }

            // -- sample: sg owns level sg; iterate heads x points --
            float ax = 0.f, ay = 0.f;
            #pragma unroll
            for (int iter = 0; iter < 16; ++iter) {
                const int hhL = iter >> 3, p = iter & 7;
                const int rec = hhL * 32 + sg * 8 + p;
                unsigned pw = sPIw[rec];
                uint2 ww = sPWw[rec];
                const __half2* vl = hhL ? vl1 : vl0;
                int idx = pw & 0x3FFF;
                int dxo = ((pw >> 14) & 1) * 16;
                int dyo = ((pw >> 15) & 1) * dyoMul;
                const __half2* b00 = vl + idx * 16;
                float2 fa = __half22float2(*(__half2*)&ww.x);   // (w00, w01)
                float2 fb = __half22float2(*(__half2*)&ww.y);   // (w10, w11)
                float2 f00 = __half22float2(b00[0]);
                float2 f01 = __half22float2(b00[dxo]);
                float2 f10 = __half22float2(b00[dyo]);
                float2 f11 = __half22float2(b00[dxo + dyo]);
                ax += fa.x * f00.x + fa.y * f01.x + fb.x * f10.x + fb.y * f11.x;
                ay += fa.x * f00.y + fa.y * f01.y + fb.x * f10.y + fb.y * f11.y;
                if ((iter & 7) == 7) {
                    // reduce over levels (sg groups) and store this head
                    float sxv = ax + __shfl_xor(ax, 16); sxv += __shfl_xor(sxv, 32);
                    float syv = ay + __shfl_xor(ay, 16); syv += __shfl_xor(syv, 32);
                    if (sg == 0)
                        *(__half2*)(preT + chunk * 264 + (2 * wv + hhL) * 32 + ch2 * 2) =
                            __floats2half2_rn(sxv, syv);
                    ax = 0.f; ay = 0.f;
                }
            }
        }
    }
    __syncthreads();

    // ---- E-stage: preT (fp16) -> bf16 hi/lo, then MFMA out projection ----
    {
        int q = t & 15, seg = t >> 4;        // row q, cols [seg*16, seg*16+16)
        const __half2* src = (const __half2*)(preT + q * 264 + seg * 16);
        short* dh = sQh + q * 264 + seg * 16;
        short* dl = sQl + q * 264 + seg * 16;
        #pragma unroll
        for (int jj = 0; jj < 8; ++jj) {
            float2 f = __half22float2(src[jj]);
            short h0 = bf16hi(f.x), h1 = bf16hi(f.y);
            dh[2 * jj]     = h0;
            dh[2 * jj + 1] = h1;
            dl[2 * jj]     = bf16hi(f.x - bf16f(h0));
            dl[2 * jj + 1] = bf16hi(f.y - bf16f(h1));
        }
    }
    __syncthreads();

    {
        f32x4 accE[4];
        f32x4 z = {0.f, 0.f, 0.f, 0.f};
        #pragma unroll
        for (int e = 0; e < 4; ++e) accE[e] = z;
        const short* outH = WtH + (768 + wv * 64 + mrow) * 256 + kg * 8;
        const short* outL = WtL + (768 + wv * 64 + mrow) * 256 + kg * 8;
        const int aoff = mrow * 264 + kg * 8;
        #pragma unroll
        for (int kk = 0; kk < 8; ++kk) {
            s16x8 ah = *(const s16x8*)(sQh + aoff + kk * 32);
            s16x8 al = *(const s16x8*)(sQl + aoff + kk * 32);
            #pragma unroll
            for (int e = 0; e < 4; ++e) {
                s16x8 bh = *(const s16x8*)(outH + e * 4096 + kk * 32);
                s16x8 bl = *(const s16x8*)(outL + e * 4096 + kk * 32);
                accE[e] = MFMA16(ah, bh, accE[e]);
                accE[e] = MFMA16(al, bh, accE[e]);
                accE[e] = MFMA16(ah, bl, accE[e]);
            }
        }
        #pragma unroll
        for (int e = 0; e < 4; ++e) {
            int col = wv * 64 + e * 16 + mrow;
            float bb = bout[col];
            #pragma unroll
            for (int r = 0; r < 4; ++r)
                out[(n0 + kg * 4 + r) * 256 + col] = accE[e][r] + bb;
        }
    }
}

// ---------------------------------------------------------------------------
extern "C" void kernel_launch(void* const* d_in, const int* in_sizes, int n_in,
                              void* d_out, int out_size, void* d_ws, size_t ws_size,
                              hipStream_t stream) {
    const float* query = (const float*)d_in[0];
    const float* refp  = (const float*)d_in[1];
    const float* f0    = (const float*)d_in[2];
    const float* f1    = (const float*)d_in[3];
    const float* f2    = (const float*)d_in[4];
    const float* f3    = (const float*)d_in[5];
    const float* Woff  = (const float*)d_in[6];
    const float* boff  = (const float*)d_in[7];
    const float* Wattn = (const float*)d_in[8];
    const float* battn = (const float*)d_in[9];
    const float* Wval  = (const float*)d_in[10];
    const float* bval  = (const float*)d_in[11];
    const float* Wout  = (const float*)d_in[12];
    const float* bout  = (const float*)d_in[13];

    __half* v  = (__half*)d_ws;                              // 11,141,120 B
    short* WtH = (short*)((char*)d_ws + 11141120);           //    524,288 B
    short* WtL = WtH + 262144;                               //    524,288 B
    float* outp = (float*)d_out;

    prep_w<<<1024, 256, 0, stream>>>(Woff, Wattn, Wout, WtH, WtL);
    vproj_kernel<<<1360, 256, 0, stream>>>(f0, f1, f2, f3, Wval, bval, v);
    msda_kernel<<<2500, 256, 0, stream>>>(query, refp, boff, battn, bout,
                                          WtH, WtL, v, outp);
}

// Round 22
// 497.429 us; speedup vs baseline: 1.0996x; 1.0025x over previous
//
#include <hip/hip_runtime.h>
#include <hip/hip_fp16.h>
#include <math.h>

// Problem constants
#define NQ 40000

typedef short s16x8 __attribute__((ext_vector_type(8)));
typedef float f32x4 __attribute__((ext_vector_type(4)));

static constexpr int HLa[4] = {128, 64, 32, 16};
static constexpr int HWa[4] = {16384, 4096, 1024, 256};
// v bases (element units): level block is [HH][Hl][Wl][32]
static constexpr int VB[4] = {0, 4194304, 5242880, 5505024};
// total v elements = 5570560

__device__ __forceinline__ short bf16hi(float x) {
    union { float f; unsigned u; } v; v.f = x;
    unsigned r = v.u + 0x7FFFu + ((v.u >> 16) & 1u);
    return (short)(r >> 16);
}
__device__ __forceinline__ float bf16f(short s) {
    union { unsigned u; float f; } v; v.u = ((unsigned)(unsigned short)s) << 16;
    return v.f;
}
__device__ __forceinline__ float fast_tanh(float x) {
    float xc = fminf(fmaxf(x, -15.f), 15.f);
    float e = __expf(2.f * xc);
    return (e - 1.f) / (e + 1.f);
}
#define MFMA16(a, b, c) __builtin_amdgcn_mfma_f32_16x16x32_bf16(a, b, c, 0, 0, 0)

// ---------------------------------------------------------------------------
// Kernel 0: weight prep — transpose [C][N] -> [N][C], bf16 hi/lo split.
// rows: [0,512) = W_off cols, [512,768) = W_attn cols, [768,1024) = W_out cols
// ---------------------------------------------------------------------------
__global__ __launch_bounds__(256) void prep_w(
    const float* __restrict__ Woff, const float* __restrict__ Wattn,
    const float* __restrict__ Wout, short* __restrict__ WtH, short* __restrict__ WtL)
{
    int r = blockIdx.x, c = threadIdx.x;
    float x;
    if (r < 512)      x = Woff[c * 512 + r];
    else if (r < 768) x = Wattn[c * 256 + (r - 512)];
    else              x = Wout[c * 256 + (r - 768)];
    short hi = bf16hi(x);
    WtH[r * 256 + c] = hi;
    WtL[r * 256 + c] = bf16hi(x - bf16f(hi));
}

// ---------------------------------------------------------------------------
// Kernel 1: value projection -> fp16 table  v[l][hh][y][x][dd]
// ---------------------------------------------------------------------------
__global__ __launch_bounds__(256) void vproj_kernel(
    const float* __restrict__ f0, const float* __restrict__ f1,
    const float* __restrict__ f2, const float* __restrict__ f3,
    const float* __restrict__ Wv, const float* __restrict__ bv,
    __half* __restrict__ v)
{
    __shared__ float fT[256 * 16];  // [c][hw] 16KB

    int bid = blockIdx.x;
    const float* f;
    int base, HWl, hw0;
    if (bid < 1024)      { f = f0; base = VB[0]; HWl = 16384; hw0 = bid * 16; }
    else if (bid < 1280) { f = f1; base = VB[1]; HWl = 4096;  hw0 = (bid - 1024) * 16; }
    else if (bid < 1344) { f = f2; base = VB[2]; HWl = 1024;  hw0 = (bid - 1280) * 16; }
    else                 { f = f3; base = VB[3]; HWl = 256;   hw0 = (bid - 1344) * 16; }

    int t = threadIdx.x;
    for (int k = 0; k < 16; ++k) {
        int idx = k * 256 + t;
        int c = idx >> 4, j = idx & 15;
        fT[idx] = f[c * HWl + hw0 + j];
    }
    __syncthreads();

    int to4 = (t & 63) * 4;
    int hw4 = (t >> 6) * 4;

    float4 bv4 = *(const float4*)(bv + to4);
    float acc[4][4];
    #pragma unroll
    for (int i = 0; i < 4; ++i) {
        acc[i][0] = bv4.x; acc[i][1] = bv4.y; acc[i][2] = bv4.z; acc[i][3] = bv4.w;
    }

    #pragma unroll 4
    for (int c = 0; c < 256; ++c) {
        float4 w4 = *(const float4*)(Wv + c * 256 + to4);
        float4 fv = *(const float4*)(fT + c * 16 + hw4);
        float fa[4] = {fv.x, fv.y, fv.z, fv.w};
        float wa[4] = {w4.x, w4.y, w4.z, w4.w};
        #pragma unroll
        for (int i = 0; i < 4; ++i)
            #pragma unroll
            for (int j = 0; j < 4; ++j)
                acc[i][j] += fa[i] * wa[j];
    }

    int hh = to4 >> 5, dd4 = to4 & 31;
    #pragma unroll
    for (int i = 0; i < 4; ++i) {
        int hw = hw0 + hw4 + i;
        __half2 h0 = __floats2half2_rn(acc[i][0], acc[i][1]);
        __half2 h1 = __floats2half2_rn(acc[i][2], acc[i][3]);
        uint2 st = make_uint2(*(unsigned*)&h0, *(unsigned*)&h1);
        *(uint2*)(v + base + (hh * HWl + hw) * 32 + dd4) = st;
    }
}

// ---------------------------------------------------------------------------
// Kernel 2: MFMA logits -> 2 superpasses {per-wave 8-query logit dump ->
//           wave-autonomous per-query pack + BATCHED gather} -> fp16 preT
//           -> MFMA out.  block = 256 threads (4 waves), 16 queries,
//           2500 blocks. LDS 28,928 B.
// EXPERIMENT: __launch_bounds__(256,2) -> 256-VGPR cap, so the 32-load
// batch per head can stay materialized (r18/r19 were capped at 128 with
// 32 accO live -> scheduler re-serialized; r20 proved >=100 VGPRs
// allocatable). sched_barrier(0) pins issue-before-blend.
// ---------------------------------------------------------------------------
__global__ __launch_bounds__(256, 2) void msda_kernel(
    const float* __restrict__ query, const float* __restrict__ refp,
    const float* __restrict__ boff,  const float* __restrict__ battn,
    const float* __restrict__ bout,
    const short* __restrict__ WtH,   const short* __restrict__ WtL,
    const __half* __restrict__ v,    float* __restrict__ out)
{
    __shared__ __align__(16) char lds[28928];
    short*    sQh  = (short*)lds;                 // [16][264] bf16 hi (stage/E)
    short*    sQl  = (short*)(lds + 8448);        // [16][264] bf16 lo (stage/E)
    __half*   sWh  = (__half*)(lds + 16896);      // [16][264] attn wts -> preT (aliased)
    float*    sR   = (float*)(lds + 28416);       // [128] ref points

    const int t = threadIdx.x;
    const int n0 = blockIdx.x * 16;
    const int wv = t >> 6, lane = t & 63;
    const int mrow = lane & 15, kg = lane >> 4;
    float*    offW = (float*)lds + wv * 1056;     // per-wave [8][132] fp32 logits
    unsigned* sPIw = (unsigned*)(lds + 25344 + wv * 768);
    uint2*    sPWw = (uint2*)(lds + 25344 + wv * 768 + 256);
    __half*   preT = sWh;                          // alias (audited: row-disjoint in time)

    // ---- Stage: query -> bf16 hi/lo LDS, ref points ----
    for (int k2 = 0; k2 < 16; ++k2) {
        float x = query[(n0 + k2) * 256 + t];
        short hi = bf16hi(x);
        sQh[k2 * 264 + t] = hi;
        sQl[k2 * 264 + t] = bf16hi(x - bf16f(hi));
    }
    if (t < 128) sR[t] = refp[n0 * 8 + t];
    __syncthreads();

    // ---- Phase B: logits via MFMA (hi/lo 3-pass for off AND attn) ----
    f32x4 accO[8], accA[4];
    {
        f32x4 z = {0.f, 0.f, 0.f, 0.f};
        #pragma unroll
        for (int j = 0; j < 8; ++j) accO[j] = z;
        #pragma unroll
        for (int j = 0; j < 4; ++j) accA[j] = z;
    }
    {
        const short* offH = WtH + (wv * 128 + mrow) * 256 + kg * 8;
        const short* offLo = WtL + (wv * 128 + mrow) * 256 + kg * 8;
        const short* attH = WtH + (512 + wv * 64 + mrow) * 256 + kg * 8;
        const short* attL = WtL + (512 + wv * 64 + mrow) * 256 + kg * 8;
        const int aoff = mrow * 264 + kg * 8;
        #pragma unroll
        for (int kk = 0; kk < 8; ++kk) {
            s16x8 ah = *(const s16x8*)(sQh + aoff + kk * 32);
            s16x8 al = *(const s16x8*)(sQl + aoff + kk * 32);
            #pragma unroll
            for (int j = 0; j < 8; ++j) {
                s16x8 bh = *(const s16x8*)(offH + j * 4096 + kk * 32);
                s16x8 bl = *(const s16x8*)(offLo + j * 4096 + kk * 32);
                accO[j] = MFMA16(ah, bh, accO[j]);
                accO[j] = MFMA16(al, bh, accO[j]);
                accO[j] = MFMA16(ah, bl, accO[j]);
            }
            #pragma unroll
            for (int ja = 0; ja < 4; ++ja) {
                s16x8 bh = *(const s16x8*)(attH + ja * 4096 + kk * 32);
                s16x8 bl = *(const s16x8*)(attL + ja * 4096 + kk * 32);
                accA[ja] = MFMA16(ah, bh, accA[ja]);
                accA[ja] = MFMA16(al, bh, accA[ja]);
                accA[ja] = MFMA16(ah, bl, accA[ja]);
            }
        }
    }
    // biases (D layout: col = mrow, rows = kg*4 + r)
    #pragma unroll
    for (int j = 0; j < 8; ++j) {
        float bb = boff[wv * 128 + j * 16 + mrow];
        #pragma unroll
        for (int r = 0; r < 4; ++r) accO[j][r] += bb;
    }
    #pragma unroll
    for (int ja = 0; ja < 4; ++ja) {
        float bb = battn[wv * 64 + ja * 16 + mrow];
        #pragma unroll
        for (int r = 0; r < 4; ++r) accA[ja][r] += bb;
    }

    // ---- Softmax over P=8 (8-lane groups), fp16 weights to sWh (own heads) ----
    #pragma unroll
    for (int ja = 0; ja < 4; ++ja) {
        int hh = 2 * wv + (ja >> 1);
        int l  = ((ja & 1) << 1) | (mrow >> 3);
        int p  = mrow & 7;
        #pragma unroll
        for (int r = 0; r < 4; ++r) {
            float x = accA[ja][r];
            float m = fmaxf(x, __shfl_xor(x, 1));
            m = fmaxf(m, __shfl_xor(m, 2));
            m = fmaxf(m, __shfl_xor(m, 4));
            float e = __expf(x - m);
            float s = e + __shfl_xor(e, 1);
            s += __shfl_xor(s, 2);
            s += __shfl_xor(s, 4);
            int q = kg * 4 + r;
            sWh[q * 264 + hh * 32 + l * 8 + p] = __float2half_rn(e / s);
        }
    }
    __syncthreads();   // all waves done reading staged q; arena becomes offW

    // ---- Chunk-loop setup ----
    // pack mapping: lane = hhL*32 + l*8 + p  (one record per lane)
    const int l_p = (lane >> 3) & 3, p_p = lane & 7, hhL_p = lane >> 5;
    const int Wl_p = 128 >> l_p;
    const float scl_p = 0.5f * (float)(Wl_p - 1);
    const int whCol = (2 * wv + hhL_p) * 32 + l_p * 8 + p_p;
    // sample mapping: sg = lane>>4 owns level sg; ch2 = lane&15 channel pair
    const int sg = kg, ch2 = mrow;
    const int Wl_s = 128 >> sg;
    const int HWs = Wl_s * Wl_s;
    const int dyoMul = Wl_s * 16;
    const int VBs = (sg == 0) ? VB[0] : (sg == 1) ? VB[1] : (sg == 2) ? VB[2] : VB[3];
    const __half2* vl0 = (const __half2*)(v + VBs + (2 * wv) * HWs * 32) + ch2;
    const __half2* vl1 = (const __half2*)(v + VBs + (2 * wv + 1) * HWs * 32) + ch2;

    // ---- 2 superpasses x 8 queries, wave-autonomous ----
    for (int sp = 0; sp < 2; ++sp) {
        // dump: lanes holding q in [8sp, 8sp+8) write their accO rows
        if ((kg >> 1) == sp) {
            #pragma unroll
            for (int j = 0; j < 8; ++j)
                #pragma unroll
                for (int r = 0; r < 4; ++r)
                    offW[((kg & 1) * 4 + r) * 132 + j * 16 + mrow] = accO[j][r];
        }

        for (int c8 = 0; c8 < 8; ++c8) {
            const int chunk = sp * 8 + c8;
            // -- pack: each lane builds one record for (q=chunk, own head) --
            {
                float2 ll = *(const float2*)(offW + c8 * 132 + 2 * lane);
                float lx = ll.x, ly = ll.y;
                float w  = __half2float(sWh[chunk * 264 + whCol]);
                float rx = sR[chunk * 8 + l_p * 2], ry = sR[chunk * 8 + l_p * 2 + 1];
                float cx = rx + fast_tanh(lx) * 0.25f;
                float cy = ry + fast_tanh(ly) * 0.25f;
                float xx = (cx + 1.f) * scl_p, yy = (cy + 1.f) * scl_p;
                float x0f = floorf(xx), y0f = floorf(yy);
                float fx = xx - x0f, fy = yy - y0f;
                int x0 = (int)x0f, y0 = (int)y0f;
                int xc0 = min(max(x0, 0), Wl_p - 1);
                int xc1 = min(max(x0 + 1, 0), Wl_p - 1);
                int yc0 = min(max(y0, 0), Wl_p - 1);
                int yc1 = min(max(y0 + 1, 0), Wl_p - 1);
                bool bx0 = (x0 >= 0) & (x0 < Wl_p);
                bool bx1 = (x0 + 1 >= 0) & (x0 + 1 < Wl_p);
                bool by0 = (y0 >= 0) & (y0 < Wl_p);
                bool by1 = (y0 + 1 >= 0) & (y0 + 1 < Wl_p);
                float w00 = (bx0 && by0) ? (1.f - fx) * (1.f - fy) * w : 0.f;
                float w01 = (bx1 && by0) ? fx * (1.f - fy) * w : 0.f;
                float w10 = (bx0 && by1) ? (1.f - fx) * fy * w : 0.f;
                float w11 = (bx1 && by1) ? fx * fy * w : 0.f;
                unsigned pw = (unsigned)(yc0 * Wl_p + xc0)
                            | ((unsigned)(xc1 - xc0) << 14)
                            | ((unsigned)(yc1 - yc0) << 15);
                sPIw[lane] = pw;
                __half2 hA = __floats2half2_rn(w00, w01);
                __half2 hB = __floats2half2_rn(w10, w11);
                sPWw[lane] = make_uint2(*(unsigned*)&hA, *(unsigned*)&hB);
            }

            // -- sample: per head, batched issue of 32 gathers (fenced), blend --
            #pragma unroll
            for (int hhL = 0; hhL < 2; ++hhL) {
                const __half2* vl = hhL ? vl1 : vl0;
                unsigned gw0[8], gw1[8], gw2[8], gw3[8];
                uint2 wwv[8];
                #pragma unroll
                for (int p = 0; p < 8; ++p) {
                    int rec = hhL * 32 + sg * 8 + p;
                    unsigned pw = sPIw[rec];
                    wwv[p] = sPWw[rec];
                    int idx = pw & 0x3FFF;
                    int dxo = ((pw >> 14) & 1) * 16;
                    int dyo = ((pw >> 15) & 1) * dyoMul;
                    const __half2* b00 = vl + idx * 16;
                    gw0[p] = *(const unsigned*)(b00);
                    gw1[p] = *(const unsigned*)(b00 + dxo);
                    gw2[p] = *(const unsigned*)(b00 + dyo);
                    gw3[p] = *(const unsigned*)(b00 + dxo + dyo);
                }
                // FENCE: keep all 32 loads issued before any blend below.
                __builtin_amdgcn_sched_barrier(0);
                float ax = 0.f, ay = 0.f;
                #pragma unroll
                for (int p = 0; p < 8; ++p) {
                    float2 fa = __half22float2(*(__half2*)&wwv[p].x);  // (w00,w01)
                    float2 fb = __half22float2(*(__half2*)&wwv[p].y);  // (w10,w11)
                    float2 f00 = __half22float2(*(__half2*)&gw0[p]);
                    float2 f01 = __half22float2(*(__half2*)&gw1[p]);
                    float2 f10 = __half22float2(*(__half2*)&gw2[p]);
                    float2 f11 = __half22float2(*(__half2*)&gw3[p]);
                    ax += fa.x * f00.x + fa.y * f01.x + fb.x * f10.x + fb.y * f11.x;
                    ay += fa.x * f00.y + fa.y * f01.y + fb.x * f10.y + fb.y * f11.y;
                }
                // reduce over levels (sg groups) and store this head
                float sxv = ax + __shfl_xor(ax, 16); sxv += __shfl_xor(sxv, 32);
                float syv = ay + __shfl_xor(ay, 16); syv += __shfl_xor(syv, 32);
                if (sg == 0)
                    *(__half2*)(preT + chunk * 264 + (2 * wv + hhL) * 32 + ch2 * 2) =
                        __floats2half2_rn(sxv, syv);
            }
        }
    }
    __syncthreads();

    // ---- E-stage: preT (fp16) -> bf16 hi/lo, then MFMA out projection ----
    {
        int q = t & 15, seg = t >> 4;        // row q, cols [seg*16, seg*16+16)
        const __half2* src = (const __half2*)(preT + q * 264 + seg * 16);
        short* dh = sQh + q * 264 + seg * 16;
        short* dl = sQl + q * 264 + seg * 16;
        #pragma unroll
        for (int jj = 0; jj < 8; ++jj) {
            float2 f = __half22float2(src[jj]);
            short h0 = bf16hi(f.x), h1 = bf16hi(f.y);
            dh[2 * jj]     = h0;
            dh[2 * jj + 1] = h1;
            dl[2 * jj]     = bf16hi(f.x - bf16f(h0));
            dl[2 * jj + 1] = bf16hi(f.y - bf16f(h1));
        }
    }
    __syncthreads();

    {
        f32x4 accE[4];
        f32x4 z = {0.f, 0.f, 0.f, 0.f};
        #pragma unroll
        for (int e = 0; e < 4; ++e) accE[e] = z;
        const short* outH = WtH + (768 + wv * 64 + mrow) * 256 + kg * 8;
        const short* outL = WtL + (768 + wv * 64 + mrow) * 256 + kg * 8;
        const int aoff = mrow * 264 + kg * 8;
        #pragma unroll
        for (int kk = 0; kk < 8; ++kk) {
            s16x8 ah = *(const s16x8*)(sQh + aoff + kk * 32);
            s16x8 al = *(const s16x8*)(sQl + aoff + kk * 32);
            #pragma unroll
            for (int e = 0; e < 4; ++e) {
                s16x8 bh = *(const s16x8*)(outH + e * 4096 + kk * 32);
                s16x8 bl = *(const s16x8*)(outL + e * 4096 + kk * 32);
                accE[e] = MFMA16(ah, bh, accE[e]);
                accE[e] = MFMA16(al, bh, accE[e]);
                accE[e] = MFMA16(ah, bl, accE[e]);
            }
        }
        #pragma unroll
        for (int e = 0; e < 4; ++e) {
            int col = wv * 64 + e * 16 + mrow;
            float bb = bout[col];
            #pragma unroll
            for (int r = 0; r < 4; ++r)
                out[(n0 + kg * 4 + r) * 256 + col] = accE[e][r] + bb;
        }
    }
}

// ---------------------------------------------------------------------------
extern "C" void kernel_launch(void* const* d_in, const int* in_sizes, int n_in,
                              void* d_out, int out_size, void* d_ws, size_t ws_size,
                              hipStream_t stream) {
    const float* query = (const float*)d_in[0];
    const float* refp  = (const float*)d_in[1];
    const float* f0    = (const float*)d_in[2];
    const float* f1    = (const float*)d_in[3];
    const float* f2    = (const float*)d_in[4];
    const float* f3    = (const float*)d_in[5];
    const float* Woff  = (const float*)d_in[6];
    const float* boff  = (const float*)d_in[7];
    const float* Wattn = (const float*)d_in[8];
    const float* battn = (const float*)d_in[9];
    const float* Wval  = (const float*)d_in[10];
    const float* bval  = (const float*)d_in[11];
    const float* Wout  = (const float*)d_in[12];
    const float* bout  = (const float*)d_in[13];

    __half* v  = (__half*)d_ws;                              // 11,141,120 B
    short* WtH = (short*)((char*)d_ws + 11141120);           //    524,288 B
    short* WtL = WtH + 262144;                               //    524,288 B
    float* outp = (float*)d_out;

    prep_w<<<1024, 256, 0, stream>>>(Woff, Wattn, Wout, WtH, WtL);
    vproj_kernel<<<1360, 256, 0, stream>>>(f0, f1, f2, f3, Wval, bval, v);
    msda_kernel<<<2500, 256, 0, stream>>>(query, refp, boff, battn, bout,
                                          WtH, WtL, v, outp);
}